// Round 8
// baseline (128.755 us; speedup 1.0000x reference)
//
#include <hip/hip_runtime.h>

// Fixed problem shape
constexpr int BS = 16, F = 4086, C = 512, SPK = 2, L = 16, STEP = 8;
constexpr int T     = (F - 1) * STEP + L;   // 32696
constexpr int ROWS  = BS * F;               // 65376
constexpr int OUT_N = BS * SPK * T;         // 1046272
constexpr int OUT4  = OUT_N / 4;            // 261568
constexpr int NT    = ROWS / 16;            // 4086 row-tiles of 16
constexpr int BLOCK = 256, TPB = 4;
constexpr int GRID_M = (NT + TPB - 1) / TPB; // 1022

typedef _Float16 f16x8 __attribute__((ext_vector_type(8)));
typedef float    f32x4 __attribute__((ext_vector_type(4)));   // clang vector: ok for nontemporal builtins
typedef __fp16   h2    __attribute__((ext_vector_type(2)));

__device__ __forceinline__ unsigned pk(float a, float b) {
    h2 r = __builtin_amdgcn_cvt_pkrtz(a, b);   // lo = a, hi = b
    return __builtin_bit_cast(unsigned, r);
}

struct Kt { f32x4 a1, a2, m1, m2, m3, m4; };  // 24 dwords

// ---- kernel 1: masked projection as MFMA GEMM -> proj[row][32] --------------
// One wave = one 16-row tile, both speakers. K=512 in 16 k-tiles of 32.
// k-map (identical for A and B, so any true-HW k-permutation cancels):
// lane g = lane>>4 owns channels c0=kt*32+8g .. c0+7; dword d = pair (c0+2d, c0+2d+1).
__global__ __launch_bounds__(BLOCK, 4) void decoder_mfma_kernel(
    const float* __restrict__ inp,    // [BS][F][C]
    const float* __restrict__ mask,   // [BS][F][C][SPK]
    const float* __restrict__ W,      // [C][L]
    float* __restrict__ proj)         // [ROWS][32]
{
    __shared__ unsigned wlds[16 * 64 * 4];   // 16 KB, B-fragment order

    const int tid = threadIdx.x;

    // ---- per-block W staging into LDS (replaces the serialized wstage kernel)
    {
        const int kt = tid >> 4, col = tid & 15;
#pragma unroll
        for (int g = 0; g < 4; ++g) {
#pragma unroll
            for (int d = 0; d < 4; ++d) {
                const int r = kt * 32 + 8 * g + 2 * d;
                const float w0 = W[r * L + col];        // 64B-coalesced per 16 lanes
                const float w1 = W[(r + 1) * L + col];
                wlds[(kt * 64 + g * 16 + col) * 4 + d] = pk(w0, w1);
            }
        }
    }
    __syncthreads();

    const int wave = tid >> 6, lane = tid & 63;
    const int tile = blockIdx.x * TPB + wave;
    if (tile >= NT) return;   // after the barrier; no further barriers below

    const int g = lane >> 4, m = lane & 15;
    const int grow = tile * 16 + m;
    const float* ip = inp  + (size_t)grow * C;
    const float* mp = mask + (size_t)grow * (C * SPK);

    auto loadkt = [&](int kt, Kt& s) {
        const float* i0 = ip + kt * 32 + 8 * g;            // 32B contiguous/lane
        s.a1 = __builtin_nontemporal_load(reinterpret_cast<const f32x4*>(i0));
        s.a2 = __builtin_nontemporal_load(reinterpret_cast<const f32x4*>(i0 + 4));
        const float* q0 = mp + kt * 64 + 16 * g;           // 64B contiguous/lane
        s.m1 = __builtin_nontemporal_load(reinterpret_cast<const f32x4*>(q0));
        s.m2 = __builtin_nontemporal_load(reinterpret_cast<const f32x4*>(q0 + 4));
        s.m3 = __builtin_nontemporal_load(reinterpret_cast<const f32x4*>(q0 + 8));
        s.m4 = __builtin_nontemporal_load(reinterpret_cast<const f32x4*>(q0 + 12));
    };

    f32x4 acc0 = {0.f, 0.f, 0.f, 0.f}, acc1 = {0.f, 0.f, 0.f, 0.f};

    auto compute = [&](int kt, const Kt& s) {
        int4 a0i, a1i;   // A fragments, speakers 0/1 (f16 pairs in k-order)
        a0i.x = pk(s.a1[0] * s.m1[0], s.a1[1] * s.m1[2]);
        a0i.y = pk(s.a1[2] * s.m2[0], s.a1[3] * s.m2[2]);
        a0i.z = pk(s.a2[0] * s.m3[0], s.a2[1] * s.m3[2]);
        a0i.w = pk(s.a2[2] * s.m4[0], s.a2[3] * s.m4[2]);
        a1i.x = pk(s.a1[0] * s.m1[1], s.a1[1] * s.m1[3]);
        a1i.y = pk(s.a1[2] * s.m2[1], s.a1[3] * s.m2[3]);
        a1i.z = pk(s.a2[0] * s.m3[1], s.a2[1] * s.m3[3]);
        a1i.w = pk(s.a2[2] * s.m4[1], s.a2[3] * s.m4[3]);
        const int4 bw = *reinterpret_cast<const int4*>(&wlds[(kt * 64 + lane) * 4]); // ds_read_b128, conflict-free
        const f16x8 bf = __builtin_bit_cast(f16x8, bw);
        acc0 = __builtin_amdgcn_mfma_f32_16x16x32_f16(__builtin_bit_cast(f16x8, a0i), bf, acc0, 0, 0, 0);
        acc1 = __builtin_amdgcn_mfma_f32_16x16x32_f16(__builtin_bit_cast(f16x8, a1i), bf, acc1, 0, 0, 0);
    };

    // explicit A/B double-buffer, hand-unrolled (no struct copies)
    Kt A, B;
    loadkt(0, A); loadkt(1, B);
    compute(0,  A); loadkt(2,  A);
    compute(1,  B); loadkt(3,  B);
    compute(2,  A); loadkt(4,  A);
    compute(3,  B); loadkt(5,  B);
    compute(4,  A); loadkt(6,  A);
    compute(5,  B); loadkt(7,  B);
    compute(6,  A); loadkt(8,  A);
    compute(7,  B); loadkt(9,  B);
    compute(8,  A); loadkt(10, A);
    compute(9,  B); loadkt(11, B);
    compute(10, A); loadkt(12, A);
    compute(11, B); loadkt(13, B);
    compute(12, A); loadkt(14, A);
    compute(13, B); loadkt(15, B);
    compute(14, A);
    compute(15, B);

    // C layout (m89-verified, r6-proven end-to-end): col = lane&15, row = g*4 + j
    const size_t base = (size_t)tile * 16 * 32;
#pragma unroll
    for (int j = 0; j < 4; ++j) {
        const int row = 4 * g + j;
        proj[base + row * 32 + m]      = acc0[j];   // speaker 0
        proj[base + row * 32 + 16 + m] = acc1[j];   // speaker 1
    }
}

// ---- kernel 2: vectorized overlap-and-add gather ----------------------------
__global__ __launch_bounds__(256) void overlap_add4_kernel(
    const float* __restrict__ proj,  // [ROWS][32]  (32 = s*16 + l)
    float* __restrict__ out)         // [BS][SPK][T]
{
    const int i4 = blockIdx.x * blockDim.x + threadIdx.x;
    if (i4 >= OUT4) return;
    const int t4 = i4 * 4;                 // SPK*T and T divisible by 4
    const int b = t4 / (SPK * T);
    const int r = t4 - b * (SPK * T);
    const int s = r / T;
    const int t = r - s * T;               // t % 4 == 0
    const int f0 = t >> 3, l0 = t & 7;     // l0 in {0,4}
    f32x4 acc = {0.f, 0.f, 0.f, 0.f};
    if (t < F * STEP)
        acc = *reinterpret_cast<const f32x4*>(&proj[(size_t)(b * F + f0) * 32 + s * 16 + l0]);
    if (t >= STEP) {
        const f32x4 p = *reinterpret_cast<const f32x4*>(&proj[(size_t)(b * F + f0 - 1) * 32 + s * 16 + 8 + l0]);
        acc += p;
    }
    *reinterpret_cast<f32x4*>(&out[t4]) = acc;
}

extern "C" void kernel_launch(void* const* d_in, const int* in_sizes, int n_in,
                              void* d_out, int out_size, void* d_ws, size_t ws_size,
                              hipStream_t stream) {
    const float* inp  = (const float*)d_in[0];
    const float* mask = (const float*)d_in[1];
    const float* W    = (const float*)d_in[2];
    float* out = (float*)d_out;

    float* proj = (float*)d_ws;   // 8.37 MB needed; ws is ample

    decoder_mfma_kernel<<<GRID_M, BLOCK, 0, stream>>>(inp, mask, W, proj);
    overlap_add4_kernel<<<(OUT4 + 255) / 256, 256, 0, stream>>>(proj, out);
}